// Round 7
// baseline (887.206 us; speedup 1.0000x reference)
//
#include <hip/hip_runtime.h>
#include <hip/hip_bf16.h>

// SAGEConv: out = x @ W_self^T + b_self + segsum(x[col]*w, row) @ W_neigh^T + b_neigh
// N=100000, E=1600000, C=64. fp32 tensors; edge_index int32 [2*E] (dst|src); out fp32.
//
// R7: R5/R6 agg (wave-per-edge broadcast gather) serialized ~6450 cyc/edge;
// R6's VGPR_Count=12 proves the 8-deep batching arrays never made it to
// registers. Rewrite agg lane-parallel: 16 lanes/edge (ushort4), one dwordx2
// gather instr covers 4 edges, meta via __shfl, no arrays, padded LDS tile.

#define C 64
#define BKT 128                 // nodes per bucket
#define TP 65                   // padded tile row stride (floats)
#define MAXB 800                // max bucket count supported by static LDS
#define BINT 6144               // edges per bin block (24 per thread)

typedef __attribute__((ext_vector_type(8))) short bf16x8;
typedef __attribute__((ext_vector_type(4))) float f32x4;

__device__ inline unsigned short f2bf(float f) {
    union { __hip_bfloat16 h; unsigned short u; } c;
    c.h = __float2bfloat16(f);
    return c.u;
}

// --------------------------------------------------------------------------
// prep: bucket histogram (LDS pre-agg) + x -> bf16 conversion.
// --------------------------------------------------------------------------
__global__ __launch_bounds__(256) void prep_kernel(
        const int* __restrict__ ei, int* __restrict__ bhist, int E, int NBK,
        const float* __restrict__ x, unsigned short* __restrict__ xb, int n4) {
    __shared__ int lh[MAXB];
    const int t = threadIdx.x;
    for (int i = t; i < NBK; i += 256) lh[i] = 0;
    __syncthreads();
    const int gtid = blockIdx.x * 256 + t;
    const int gs = gridDim.x * 256;
    for (int e = gtid; e < E; e += gs)
        atomicAdd(&lh[ei[e] >> 7], 1);
    __syncthreads();
    for (int i = t; i < NBK; i += 256)
        if (lh[i]) atomicAdd(&bhist[i], lh[i]);
    const float4* x4 = (const float4*)x;
    ushort4* xb4 = (ushort4*)xb;
    for (int i = gtid; i < n4; i += gs) {
        float4 v = x4[i];
        ushort4 o;
        o.x = f2bf(v.x); o.y = f2bf(v.y); o.z = f2bf(v.z); o.w = f2bf(v.w);
        xb4[i] = o;
    }
}

// --------------------------------------------------------------------------
// scan: exclusive scan of bhist[NBK] -> boffs[NBK+1], copy to bcur. 1 block.
// --------------------------------------------------------------------------
__global__ __launch_bounds__(1024) void scan_kernel(
        const int* __restrict__ bhist, int* __restrict__ boffs,
        int* __restrict__ bcur, int NBK) {
    __shared__ int s[1024];
    const int t = threadIdx.x;
    s[t] = (t < NBK) ? bhist[t] : 0;
    __syncthreads();
    for (int off = 1; off < 1024; off <<= 1) {
        int v = 0;
        if (t >= off) v = s[t - off];
        __syncthreads();
        if (t >= off) s[t] += v;
        __syncthreads();
    }
    if (t < NBK) {
        int e = (t > 0) ? s[t - 1] : 0;
        boffs[t] = e;
        bcur[t] = e;
        if (t == NBK - 1) boffs[NBK] = s[t];
    }
}

// --------------------------------------------------------------------------
// bin: coarse counting sort by 128-node bucket, LDS-staged coalesced writes.
// --------------------------------------------------------------------------
__global__ __launch_bounds__(256) void bin_kernel(
        const int* __restrict__ ei, const float* __restrict__ ew,
        int* __restrict__ bcur, const int* __restrict__ unused,
        int2* __restrict__ sorted, int E, int NBK) {
    __shared__ int2 stage[BINT];            // 48 KB
    __shared__ int h[MAXB];
    __shared__ int ls[MAXB + 1];
    __shared__ int gb[MAXB];
    __shared__ int cur[MAXB];
    __shared__ int part[256];

    const int t = threadIdx.x;
    const int e0 = blockIdx.x * BINT;
    const int cnt = min(BINT, E - e0);

    for (int i = t; i < NBK; i += 256) h[i] = 0;
    __syncthreads();

#pragma unroll
    for (int k = 0; k < BINT / 256; ++k) {
        const int e = e0 + t + k * 256;
        if (e - e0 < cnt) atomicAdd(&h[ei[e] >> 7], 1);
    }
    __syncthreads();

    int vloc[4]; int s0 = 0;
#pragma unroll
    for (int k = 0; k < 4; ++k) {
        const int idx = t * 4 + k;
        vloc[k] = (idx < NBK) ? h[idx] : 0;
        s0 += vloc[k];
    }
    part[t] = s0;
    __syncthreads();
    for (int off = 1; off < 256; off <<= 1) {
        int v = 0;
        if (t >= off) v = part[t - off];
        __syncthreads();
        if (t >= off) part[t] += v;
        __syncthreads();
    }
    int run = (t > 0) ? part[t - 1] : 0;
#pragma unroll
    for (int k = 0; k < 4; ++k) {
        const int idx = t * 4 + k;
        if (idx < NBK) ls[idx] = run;
        run += vloc[k];
    }
    if (t == 255) ls[NBK] = part[255];
    __syncthreads();

    for (int i = t; i < NBK; i += 256) {
        const int hh = ls[i + 1] - ls[i];
        gb[i] = hh ? atomicAdd(&bcur[i], hh) : 0;
        cur[i] = ls[i];
    }
    __syncthreads();

#pragma unroll
    for (int k = 0; k < BINT / 256; ++k) {
        const int e = e0 + t + k * 256;
        if (e - e0 < cnt) {
            const int d = ei[e];
            const int s = ei[E + e];
            const float w = ew[e];
            const int b = d >> 7;
            const int dl = d & 127;
            const int p = atomicAdd(&cur[b], 1);
            stage[p] = make_int2((dl << 17) | s, __float_as_int(w));
        }
    }
    __syncthreads();

    for (int i = t; i < cnt; i += 256) {
        int lo = 0, hi = NBK - 1;
#pragma unroll
        for (int it = 0; it < 10; ++it) {
            const int mid = (lo + hi + 1) >> 1;
            if (ls[mid] <= i) lo = mid; else hi = mid - 1;
        }
        sorted[gb[lo] + (i - ls[lo])] = stage[i];
    }
}

// --------------------------------------------------------------------------
// agg v3 (lane-parallel): one block per bucket, 8 waves; 128 x 65-padded fp32
// tile in LDS (33.3 KB). Per wave batch: 64 edges' meta coalesced into lanes.
// Group g handles 4 edges: lane i -> edge 4g+(i>>4), channels 4*(i&15)..+3.
// One ushort4 gather instr covers 4 edges (4 x 128B lines). Meta via __shfl
// (no scalar loads, no register arrays -> no spill). unroll 4 => 4 chains
// in flight. Pad 65 spreads the 4 rows across banks (dl%32 shift).
// --------------------------------------------------------------------------
__global__ __launch_bounds__(512) void agg_kernel(
        const unsigned short* __restrict__ xb,
        const int2* __restrict__ sorted,
        const int* __restrict__ boffs,
        float* __restrict__ agg, int N) {
    __shared__ float tile[BKT * TP];        // 33.3 KB
    const int t = threadIdx.x;
    const int b = blockIdx.x;
    const int node0 = b << 7;

    for (int i = t; i < BKT * TP; i += 512) tile[i] = 0.f;
    __syncthreads();

    const int lane = t & 63;
    const int wv = t >> 6;                  // 0..7
    const int sub = lane >> 4;              // edge slot within group (0..3)
    const int ch4 = (lane & 15) * 4;        // channel base (0,4,..,60)
    const int beg = boffs[b];
    const int end = boffs[b + 1];

    for (int base = beg + wv * 64; base < end; base += 8 * 64) {
        int2 meta = make_int2(0, 0);        // guard lanes: w=0 -> +0 to row 0
        if (base + lane < end) meta = sorted[base + lane];
#pragma unroll 4
        for (int g = 0; g < 16; ++g) {
            const int mx = __shfl(meta.x, 4 * g + sub);
            const float w = __int_as_float(__shfl(meta.y, 4 * g + sub));
            const int src = mx & 0x1FFFF;
            const int dl = mx >> 17;
            const ushort4 u = *(const ushort4*)(xb + (size_t)src * C + ch4);
            float* row = &tile[dl * TP + ch4];
            atomicAdd(row + 0, w * __int_as_float(((int)u.x) << 16));
            atomicAdd(row + 1, w * __int_as_float(((int)u.y) << 16));
            atomicAdd(row + 2, w * __int_as_float(((int)u.z) << 16));
            atomicAdd(row + 3, w * __int_as_float(((int)u.w) << 16));
        }
    }
    __syncthreads();

    const int rows = min(BKT, N - node0);
    float* aggb = agg + (size_t)node0 * C;
    for (int i = t; i < rows * C; i += 512)
        aggb[i] = tile[(i >> 6) * TP + (i & 63)];    // coalesced global writes
}

// --------------------------------------------------------------------------
// fallback (ws too small / N too big): R2 atomic scatter.
// --------------------------------------------------------------------------
__global__ __launch_bounds__(256) void scatter_kernel(
        const float* __restrict__ x, const int* __restrict__ ei,
        const float* __restrict__ ew, float* __restrict__ agg, int E) {
    const int lane = threadIdx.x & 63;
    const int wid = (blockIdx.x * blockDim.x + threadIdx.x) >> 6;
    const int nw = (gridDim.x * blockDim.x) >> 6;
    for (int base = wid * 64; base < E; base += nw * 64) {
        const int e = base + lane;
        int dst = 0, src = 0; float w = 0.f;
        if (e < E) { dst = ei[e]; src = ei[E + e]; w = ew[e]; }
        const int cnt = min(64, E - base);
        for (int j = 0; j < cnt; ++j) {
            const int d = __shfl(dst, j);
            const int s = __shfl(src, j);
            const float wj = __shfl(w, j);
            atomicAdd(&agg[d * C + lane], x[s * C + lane] * wj);
        }
    }
}

// --------------------------------------------------------------------------
// proj: out = [x | agg] @ [Ws | Wn]^T + bias as K=128 bf16 MFMA GEMM.
// --------------------------------------------------------------------------
__device__ inline bf16x8 cvt8(const float* __restrict__ p) {
    f32x4 lo = *(const f32x4*)p;
    f32x4 hi = *(const f32x4*)(p + 4);
    union { bf16x8 v; __hip_bfloat16 e[8]; } u;
#pragma unroll
    for (int j = 0; j < 4; ++j) u.e[j] = __float2bfloat16(lo[j]);
#pragma unroll
    for (int j = 0; j < 4; ++j) u.e[4 + j] = __float2bfloat16(hi[j]);
    return u.v;
}

__global__ __launch_bounds__(256) void proj_kernel(
        const float* __restrict__ x, const float* __restrict__ agg,
        const float* __restrict__ Ws, const float* __restrict__ bs,
        const float* __restrict__ Wn, const float* __restrict__ bn,
        float* __restrict__ out, int N) {
    const int lane = threadIdx.x & 63;
    const int wid = (blockIdx.x * blockDim.x + threadIdx.x) >> 6;
    const int l15 = lane & 15;
    const int quad = lane >> 4;
    const int nTiles = N >> 4;
    if (wid >= nTiles) return;
    const int m0 = wid << 4;

    bf16x8 bsf[4][2], bnf[4][2];
#pragma unroll
    for (int tt = 0; tt < 4; ++tt) {
        const int o = tt * 16 + l15;
#pragma unroll
        for (int h = 0; h < 2; ++h) {
            bsf[tt][h] = cvt8(Ws + o * C + h * 32 + quad * 8);
            bnf[tt][h] = cvt8(Wn + o * C + h * 32 + quad * 8);
        }
    }

    const int m = m0 + l15;
    bf16x8 ax[2], ag[2];
#pragma unroll
    for (int h = 0; h < 2; ++h) {
        ax[h] = cvt8(x + m * C + h * 32 + quad * 8);
        ag[h] = cvt8(agg + m * C + h * 32 + quad * 8);
    }

#pragma unroll
    for (int tt = 0; tt < 4; ++tt) {
        f32x4 acc = {0.f, 0.f, 0.f, 0.f};
        acc = __builtin_amdgcn_mfma_f32_16x16x32_bf16(ax[0], bsf[tt][0], acc, 0, 0, 0);
        acc = __builtin_amdgcn_mfma_f32_16x16x32_bf16(ax[1], bsf[tt][1], acc, 0, 0, 0);
        acc = __builtin_amdgcn_mfma_f32_16x16x32_bf16(ag[0], bnf[tt][0], acc, 0, 0, 0);
        acc = __builtin_amdgcn_mfma_f32_16x16x32_bf16(ag[1], bnf[tt][1], acc, 0, 0, 0);
        const int o = tt * 16 + l15;
        const float bias = bs[o] + bn[o];
#pragma unroll
        for (int r = 0; r < 4; ++r)
            out[(m0 + quad * 4 + r) * C + o] = acc[r] + bias;
    }
}

extern "C" void kernel_launch(void* const* d_in, const int* in_sizes, int n_in,
                              void* d_out, int out_size, void* d_ws, size_t ws_size,
                              hipStream_t stream) {
    const float* x  = (const float*)d_in[0];
    const int*   ei = (const int*)d_in[1];
    const float* ew = (const float*)d_in[2];
    const float* Ws = (const float*)d_in[3];
    const float* bs = (const float*)d_in[4];
    const float* Wn = (const float*)d_in[5];
    const float* bn = (const float*)d_in[6];

    const int N = in_sizes[0] / C;   // 100000
    const int E = in_sizes[2];       // 1600000
    const int NBK = (N + BKT - 1) / BKT;   // 782

    char* p = (char*)d_ws;
    float* agg = (float*)p;                 p += (size_t)N * C * sizeof(float);   // 25.6MB
    unsigned short* xb = (unsigned short*)p; p += (size_t)N * C * sizeof(short);  // 12.8MB
    int2* sorted = (int2*)p;                p += (size_t)E * sizeof(int2);        // 12.8MB
    int* bhist = (int*)p;                   p += (size_t)MAXB * sizeof(int);
    int* boffs = (int*)p;                   p += (size_t)(MAXB + 1) * sizeof(int);
    int* bcur = (int*)p;                    p += (size_t)MAXB * sizeof(int);
    const size_t needed = (size_t)(p - (char*)d_ws);

    const int nTiles = N / 16;
    const int projBlocks = (nTiles + 3) / 4;

    if (needed <= ws_size && N <= (1 << 17) && NBK <= MAXB) {
        const int n4 = N * C / 4;
        hipMemsetAsync(bhist, 0, (size_t)NBK * sizeof(int), stream);
        prep_kernel<<<256, 256, 0, stream>>>(ei, bhist, E, NBK, x, xb, n4);
        scan_kernel<<<1, 1024, 0, stream>>>(bhist, boffs, bcur, NBK);
        bin_kernel<<<(E + BINT - 1) / BINT, 256, 0, stream>>>(ei, ew, bcur, bhist,
                                                              sorted, E, NBK);
        agg_kernel<<<NBK, 512, 0, stream>>>(xb, sorted, boffs, agg, N);
    } else {
        hipMemsetAsync(agg, 0, (size_t)N * C * sizeof(float), stream);
        scatter_kernel<<<2048, 256, 0, stream>>>(x, ei, ew, agg, E);
    }

    proj_kernel<<<projBlocks, 256, 0, stream>>>(x, agg, Ws, bs, Wn, bn,
                                                (float*)d_out, N);
}

// Round 8
// 884.254 us; speedup vs baseline: 1.0033x; 1.0033x over previous
//
#include <hip/hip_runtime.h>
#include <hip/hip_bf16.h>

// SAGEConv: out = x @ W_self^T + b_self + segsum(x[col]*w, row) @ W_neigh^T + b_neigh
// N=100000, E=1600000, C=64. fp32 tensors; edge_index int32 [2*E] (dst|src); out fp32.
//
// R8: R5/R6/R7 agg all ~690us despite three different instruction streams ->
// the invariant op is 102.4M fp32 LDS atomicAdd. Theory: default atomicAdd on
// LDS fp32 compiles to a CAS retry loop (no -munsafe-fp-atomics). Fix: HIP's
// unsafeAtomicAdd -> native ds_add_f32. Only change vs R7.

#define C 64
#define BKT 128                 // nodes per bucket
#define TP 65                   // padded tile row stride (floats)
#define MAXB 800                // max bucket count supported by static LDS
#define BINT 6144               // edges per bin block (24 per thread)

typedef __attribute__((ext_vector_type(8))) short bf16x8;
typedef __attribute__((ext_vector_type(4))) float f32x4;

__device__ inline unsigned short f2bf(float f) {
    union { __hip_bfloat16 h; unsigned short u; } c;
    c.h = __float2bfloat16(f);
    return c.u;
}

// --------------------------------------------------------------------------
// prep: bucket histogram (LDS pre-agg) + x -> bf16 conversion.
// --------------------------------------------------------------------------
__global__ __launch_bounds__(256) void prep_kernel(
        const int* __restrict__ ei, int* __restrict__ bhist, int E, int NBK,
        const float* __restrict__ x, unsigned short* __restrict__ xb, int n4) {
    __shared__ int lh[MAXB];
    const int t = threadIdx.x;
    for (int i = t; i < NBK; i += 256) lh[i] = 0;
    __syncthreads();
    const int gtid = blockIdx.x * 256 + t;
    const int gs = gridDim.x * 256;
    for (int e = gtid; e < E; e += gs)
        atomicAdd(&lh[ei[e] >> 7], 1);
    __syncthreads();
    for (int i = t; i < NBK; i += 256)
        if (lh[i]) atomicAdd(&bhist[i], lh[i]);
    const float4* x4 = (const float4*)x;
    ushort4* xb4 = (ushort4*)xb;
    for (int i = gtid; i < n4; i += gs) {
        float4 v = x4[i];
        ushort4 o;
        o.x = f2bf(v.x); o.y = f2bf(v.y); o.z = f2bf(v.z); o.w = f2bf(v.w);
        xb4[i] = o;
    }
}

// --------------------------------------------------------------------------
// scan: exclusive scan of bhist[NBK] -> boffs[NBK+1], copy to bcur. 1 block.
// --------------------------------------------------------------------------
__global__ __launch_bounds__(1024) void scan_kernel(
        const int* __restrict__ bhist, int* __restrict__ boffs,
        int* __restrict__ bcur, int NBK) {
    __shared__ int s[1024];
    const int t = threadIdx.x;
    s[t] = (t < NBK) ? bhist[t] : 0;
    __syncthreads();
    for (int off = 1; off < 1024; off <<= 1) {
        int v = 0;
        if (t >= off) v = s[t - off];
        __syncthreads();
        if (t >= off) s[t] += v;
        __syncthreads();
    }
    if (t < NBK) {
        int e = (t > 0) ? s[t - 1] : 0;
        boffs[t] = e;
        bcur[t] = e;
        if (t == NBK - 1) boffs[NBK] = s[t];
    }
}

// --------------------------------------------------------------------------
// bin: coarse counting sort by 128-node bucket, LDS-staged coalesced writes.
// --------------------------------------------------------------------------
__global__ __launch_bounds__(256) void bin_kernel(
        const int* __restrict__ ei, const float* __restrict__ ew,
        int* __restrict__ bcur, const int* __restrict__ unused,
        int2* __restrict__ sorted, int E, int NBK) {
    __shared__ int2 stage[BINT];            // 48 KB
    __shared__ int h[MAXB];
    __shared__ int ls[MAXB + 1];
    __shared__ int gb[MAXB];
    __shared__ int cur[MAXB];
    __shared__ int part[256];

    const int t = threadIdx.x;
    const int e0 = blockIdx.x * BINT;
    const int cnt = min(BINT, E - e0);

    for (int i = t; i < NBK; i += 256) h[i] = 0;
    __syncthreads();

#pragma unroll
    for (int k = 0; k < BINT / 256; ++k) {
        const int e = e0 + t + k * 256;
        if (e - e0 < cnt) atomicAdd(&h[ei[e] >> 7], 1);
    }
    __syncthreads();

    int vloc[4]; int s0 = 0;
#pragma unroll
    for (int k = 0; k < 4; ++k) {
        const int idx = t * 4 + k;
        vloc[k] = (idx < NBK) ? h[idx] : 0;
        s0 += vloc[k];
    }
    part[t] = s0;
    __syncthreads();
    for (int off = 1; off < 256; off <<= 1) {
        int v = 0;
        if (t >= off) v = part[t - off];
        __syncthreads();
        if (t >= off) part[t] += v;
        __syncthreads();
    }
    int run = (t > 0) ? part[t - 1] : 0;
#pragma unroll
    for (int k = 0; k < 4; ++k) {
        const int idx = t * 4 + k;
        if (idx < NBK) ls[idx] = run;
        run += vloc[k];
    }
    if (t == 255) ls[NBK] = part[255];
    __syncthreads();

    for (int i = t; i < NBK; i += 256) {
        const int hh = ls[i + 1] - ls[i];
        gb[i] = hh ? atomicAdd(&bcur[i], hh) : 0;
        cur[i] = ls[i];
    }
    __syncthreads();

#pragma unroll
    for (int k = 0; k < BINT / 256; ++k) {
        const int e = e0 + t + k * 256;
        if (e - e0 < cnt) {
            const int d = ei[e];
            const int s = ei[E + e];
            const float w = ew[e];
            const int b = d >> 7;
            const int dl = d & 127;
            const int p = atomicAdd(&cur[b], 1);
            stage[p] = make_int2((dl << 17) | s, __float_as_int(w));
        }
    }
    __syncthreads();

    for (int i = t; i < cnt; i += 256) {
        int lo = 0, hi = NBK - 1;
#pragma unroll
        for (int it = 0; it < 10; ++it) {
            const int mid = (lo + hi + 1) >> 1;
            if (ls[mid] <= i) lo = mid; else hi = mid - 1;
        }
        sorted[gb[lo] + (i - ls[lo])] = stage[i];
    }
}

// --------------------------------------------------------------------------
// agg v4: identical to R7's lane-parallel structure, but native ds_add_f32
// via unsafeAtomicAdd (plain fp32 LDS atomicAdd is a CAS loop by default).
// --------------------------------------------------------------------------
__global__ __launch_bounds__(512) void agg_kernel(
        const unsigned short* __restrict__ xb,
        const int2* __restrict__ sorted,
        const int* __restrict__ boffs,
        float* __restrict__ agg, int N) {
    __shared__ float tile[BKT * TP];        // 33.3 KB
    const int t = threadIdx.x;
    const int b = blockIdx.x;
    const int node0 = b << 7;

    for (int i = t; i < BKT * TP; i += 512) tile[i] = 0.f;
    __syncthreads();

    const int lane = t & 63;
    const int wv = t >> 6;                  // 0..7
    const int sub = lane >> 4;              // edge slot within group (0..3)
    const int ch4 = (lane & 15) * 4;        // channel base (0,4,..,60)
    const int beg = boffs[b];
    const int end = boffs[b + 1];

    for (int base = beg + wv * 64; base < end; base += 8 * 64) {
        int2 meta = make_int2(0, 0);        // guard lanes: w=0 -> +0 to row 0
        if (base + lane < end) meta = sorted[base + lane];
#pragma unroll 4
        for (int g = 0; g < 16; ++g) {
            const int mx = __shfl(meta.x, 4 * g + sub);
            const float w = __int_as_float(__shfl(meta.y, 4 * g + sub));
            const int src = mx & 0x1FFFF;
            const int dl = mx >> 17;
            const ushort4 u = *(const ushort4*)(xb + (size_t)src * C + ch4);
            float* row = &tile[dl * TP + ch4];
            unsafeAtomicAdd(row + 0, w * __int_as_float(((int)u.x) << 16));
            unsafeAtomicAdd(row + 1, w * __int_as_float(((int)u.y) << 16));
            unsafeAtomicAdd(row + 2, w * __int_as_float(((int)u.z) << 16));
            unsafeAtomicAdd(row + 3, w * __int_as_float(((int)u.w) << 16));
        }
    }
    __syncthreads();

    const int rows = min(BKT, N - node0);
    float* aggb = agg + (size_t)node0 * C;
    for (int i = t; i < rows * C; i += 512)
        aggb[i] = tile[(i >> 6) * TP + (i & 63)];    // coalesced global writes
}

// --------------------------------------------------------------------------
// fallback (ws too small / N too big): R2 atomic scatter.
// --------------------------------------------------------------------------
__global__ __launch_bounds__(256) void scatter_kernel(
        const float* __restrict__ x, const int* __restrict__ ei,
        const float* __restrict__ ew, float* __restrict__ agg, int E) {
    const int lane = threadIdx.x & 63;
    const int wid = (blockIdx.x * blockDim.x + threadIdx.x) >> 6;
    const int nw = (gridDim.x * blockDim.x) >> 6;
    for (int base = wid * 64; base < E; base += nw * 64) {
        const int e = base + lane;
        int dst = 0, src = 0; float w = 0.f;
        if (e < E) { dst = ei[e]; src = ei[E + e]; w = ew[e]; }
        const int cnt = min(64, E - base);
        for (int j = 0; j < cnt; ++j) {
            const int d = __shfl(dst, j);
            const int s = __shfl(src, j);
            const float wj = __shfl(w, j);
            atomicAdd(&agg[d * C + lane], x[s * C + lane] * wj);
        }
    }
}

// --------------------------------------------------------------------------
// proj: out = [x | agg] @ [Ws | Wn]^T + bias as K=128 bf16 MFMA GEMM.
// --------------------------------------------------------------------------
__device__ inline bf16x8 cvt8(const float* __restrict__ p) {
    f32x4 lo = *(const f32x4*)p;
    f32x4 hi = *(const f32x4*)(p + 4);
    union { bf16x8 v; __hip_bfloat16 e[8]; } u;
#pragma unroll
    for (int j = 0; j < 4; ++j) u.e[j] = __float2bfloat16(lo[j]);
#pragma unroll
    for (int j = 0; j < 4; ++j) u.e[4 + j] = __float2bfloat16(hi[j]);
    return u.v;
}

__global__ __launch_bounds__(256) void proj_kernel(
        const float* __restrict__ x, const float* __restrict__ agg,
        const float* __restrict__ Ws, const float* __restrict__ bs,
        const float* __restrict__ Wn, const float* __restrict__ bn,
        float* __restrict__ out, int N) {
    const int lane = threadIdx.x & 63;
    const int wid = (blockIdx.x * blockDim.x + threadIdx.x) >> 6;
    const int l15 = lane & 15;
    const int quad = lane >> 4;
    const int nTiles = N >> 4;
    if (wid >= nTiles) return;
    const int m0 = wid << 4;

    bf16x8 bsf[4][2], bnf[4][2];
#pragma unroll
    for (int tt = 0; tt < 4; ++tt) {
        const int o = tt * 16 + l15;
#pragma unroll
        for (int h = 0; h < 2; ++h) {
            bsf[tt][h] = cvt8(Ws + o * C + h * 32 + quad * 8);
            bnf[tt][h] = cvt8(Wn + o * C + h * 32 + quad * 8);
        }
    }

    const int m = m0 + l15;
    bf16x8 ax[2], ag[2];
#pragma unroll
    for (int h = 0; h < 2; ++h) {
        ax[h] = cvt8(x + m * C + h * 32 + quad * 8);
        ag[h] = cvt8(agg + m * C + h * 32 + quad * 8);
    }

#pragma unroll
    for (int tt = 0; tt < 4; ++tt) {
        f32x4 acc = {0.f, 0.f, 0.f, 0.f};
        acc = __builtin_amdgcn_mfma_f32_16x16x32_bf16(ax[0], bsf[tt][0], acc, 0, 0, 0);
        acc = __builtin_amdgcn_mfma_f32_16x16x32_bf16(ax[1], bsf[tt][1], acc, 0, 0, 0);
        acc = __builtin_amdgcn_mfma_f32_16x16x32_bf16(ag[0], bnf[tt][0], acc, 0, 0, 0);
        acc = __builtin_amdgcn_mfma_f32_16x16x32_bf16(ag[1], bnf[tt][1], acc, 0, 0, 0);
        const int o = tt * 16 + l15;
        const float bias = bs[o] + bn[o];
#pragma unroll
        for (int r = 0; r < 4; ++r)
            out[(m0 + quad * 4 + r) * C + o] = acc[r] + bias;
    }
}

extern "C" void kernel_launch(void* const* d_in, const int* in_sizes, int n_in,
                              void* d_out, int out_size, void* d_ws, size_t ws_size,
                              hipStream_t stream) {
    const float* x  = (const float*)d_in[0];
    const int*   ei = (const int*)d_in[1];
    const float* ew = (const float*)d_in[2];
    const float* Ws = (const float*)d_in[3];
    const float* bs = (const float*)d_in[4];
    const float* Wn = (const float*)d_in[5];
    const float* bn = (const float*)d_in[6];

    const int N = in_sizes[0] / C;   // 100000
    const int E = in_sizes[2];       // 1600000
    const int NBK = (N + BKT - 1) / BKT;   // 782

    char* p = (char*)d_ws;
    float* agg = (float*)p;                 p += (size_t)N * C * sizeof(float);   // 25.6MB
    unsigned short* xb = (unsigned short*)p; p += (size_t)N * C * sizeof(short);  // 12.8MB
    int2* sorted = (int2*)p;                p += (size_t)E * sizeof(int2);        // 12.8MB
    int* bhist = (int*)p;                   p += (size_t)MAXB * sizeof(int);
    int* boffs = (int*)p;                   p += (size_t)(MAXB + 1) * sizeof(int);
    int* bcur = (int*)p;                    p += (size_t)MAXB * sizeof(int);
    const size_t needed = (size_t)(p - (char*)d_ws);

    const int nTiles = N / 16;
    const int projBlocks = (nTiles + 3) / 4;

    if (needed <= ws_size && N <= (1 << 17) && NBK <= MAXB) {
        const int n4 = N * C / 4;
        hipMemsetAsync(bhist, 0, (size_t)NBK * sizeof(int), stream);
        prep_kernel<<<256, 256, 0, stream>>>(ei, bhist, E, NBK, x, xb, n4);
        scan_kernel<<<1, 1024, 0, stream>>>(bhist, boffs, bcur, NBK);
        bin_kernel<<<(E + BINT - 1) / BINT, 256, 0, stream>>>(ei, ew, bcur, bhist,
                                                              sorted, E, NBK);
        agg_kernel<<<NBK, 512, 0, stream>>>(xb, sorted, boffs, agg, N);
    } else {
        hipMemsetAsync(agg, 0, (size_t)N * C * sizeof(float), stream);
        scatter_kernel<<<2048, 256, 0, stream>>>(x, ei, ew, agg, E);
    }

    proj_kernel<<<projBlocks, 256, 0, stream>>>(x, agg, Ws, bs, Wn, bn,
                                                (float*)d_out, N);
}

// Round 9
// 256.382 us; speedup vs baseline: 3.4605x; 3.4490x over previous
//
#include <hip/hip_runtime.h>
#include <hip/hip_bf16.h>

// SAGEConv: out = x @ W_self^T + b_self + segsum(x[col]*w, row) @ W_neigh^T + b_neigh
// N=100000, E=1600000, C=64. fp32 tensors; edge_index int32 [2*E] (dst|src); out fp32.
//
// R9: R5-R8 proved fp32 LDS atomicAdd is ~6500 cyc/edge on this part regardless
// of instruction stream; everything without it ran fast. New agg: fine counting
// sort in LDS (int atomics only) + per-dst-segment REGISTER accumulation
// (R3/R4's proven-fast pattern), direct row writes. Zero fp32 atomics.

#define C 64
#define BKT 128                 // nodes per bucket
#define MAXB 800                // max bucket count supported by static LDS
#define BINT 6144               // edges per bin block (24 per thread)
#define CAP 2560                // agg: edges sorted per chunk (bucket avg 2046, max ~2200)

typedef __attribute__((ext_vector_type(8))) short bf16x8;
typedef __attribute__((ext_vector_type(4))) float f32x4;

__device__ inline unsigned short f2bf(float f) {
    union { __hip_bfloat16 h; unsigned short u; } c;
    c.h = __float2bfloat16(f);
    return c.u;
}

// --------------------------------------------------------------------------
// prep: bucket histogram (LDS pre-agg) + x -> bf16 conversion.
// --------------------------------------------------------------------------
__global__ __launch_bounds__(256) void prep_kernel(
        const int* __restrict__ ei, int* __restrict__ bhist, int E, int NBK,
        const float* __restrict__ x, unsigned short* __restrict__ xb, int n4) {
    __shared__ int lh[MAXB];
    const int t = threadIdx.x;
    for (int i = t; i < NBK; i += 256) lh[i] = 0;
    __syncthreads();
    const int gtid = blockIdx.x * 256 + t;
    const int gs = gridDim.x * 256;
    for (int e = gtid; e < E; e += gs)
        atomicAdd(&lh[ei[e] >> 7], 1);
    __syncthreads();
    for (int i = t; i < NBK; i += 256)
        if (lh[i]) atomicAdd(&bhist[i], lh[i]);
    const float4* x4 = (const float4*)x;
    ushort4* xb4 = (ushort4*)xb;
    for (int i = gtid; i < n4; i += gs) {
        float4 v = x4[i];
        ushort4 o;
        o.x = f2bf(v.x); o.y = f2bf(v.y); o.z = f2bf(v.z); o.w = f2bf(v.w);
        xb4[i] = o;
    }
}

// --------------------------------------------------------------------------
// scan: exclusive scan of bhist[NBK] -> boffs[NBK+1], copy to bcur. 1 block.
// --------------------------------------------------------------------------
__global__ __launch_bounds__(1024) void scan_kernel(
        const int* __restrict__ bhist, int* __restrict__ boffs,
        int* __restrict__ bcur, int NBK) {
    __shared__ int s[1024];
    const int t = threadIdx.x;
    s[t] = (t < NBK) ? bhist[t] : 0;
    __syncthreads();
    for (int off = 1; off < 1024; off <<= 1) {
        int v = 0;
        if (t >= off) v = s[t - off];
        __syncthreads();
        if (t >= off) s[t] += v;
        __syncthreads();
    }
    if (t < NBK) {
        int e = (t > 0) ? s[t - 1] : 0;
        boffs[t] = e;
        bcur[t] = e;
        if (t == NBK - 1) boffs[NBK] = s[t];
    }
}

// --------------------------------------------------------------------------
// bin: coarse counting sort by 128-node bucket, LDS-staged coalesced writes.
// --------------------------------------------------------------------------
__global__ __launch_bounds__(256) void bin_kernel(
        const int* __restrict__ ei, const float* __restrict__ ew,
        int* __restrict__ bcur, const int* __restrict__ unused,
        int2* __restrict__ sorted, int E, int NBK) {
    __shared__ int2 stage[BINT];            // 48 KB
    __shared__ int h[MAXB];
    __shared__ int ls[MAXB + 1];
    __shared__ int gb[MAXB];
    __shared__ int cur[MAXB];
    __shared__ int part[256];

    const int t = threadIdx.x;
    const int e0 = blockIdx.x * BINT;
    const int cnt = min(BINT, E - e0);

    for (int i = t; i < NBK; i += 256) h[i] = 0;
    __syncthreads();

#pragma unroll
    for (int k = 0; k < BINT / 256; ++k) {
        const int e = e0 + t + k * 256;
        if (e - e0 < cnt) atomicAdd(&h[ei[e] >> 7], 1);
    }
    __syncthreads();

    int vloc[4]; int s0 = 0;
#pragma unroll
    for (int k = 0; k < 4; ++k) {
        const int idx = t * 4 + k;
        vloc[k] = (idx < NBK) ? h[idx] : 0;
        s0 += vloc[k];
    }
    part[t] = s0;
    __syncthreads();
    for (int off = 1; off < 256; off <<= 1) {
        int v = 0;
        if (t >= off) v = part[t - off];
        __syncthreads();
        if (t >= off) part[t] += v;
        __syncthreads();
    }
    int run = (t > 0) ? part[t - 1] : 0;
#pragma unroll
    for (int k = 0; k < 4; ++k) {
        const int idx = t * 4 + k;
        if (idx < NBK) ls[idx] = run;
        run += vloc[k];
    }
    if (t == 255) ls[NBK] = part[255];
    __syncthreads();

    for (int i = t; i < NBK; i += 256) {
        const int hh = ls[i + 1] - ls[i];
        gb[i] = hh ? atomicAdd(&bcur[i], hh) : 0;
        cur[i] = ls[i];
    }
    __syncthreads();

#pragma unroll
    for (int k = 0; k < BINT / 256; ++k) {
        const int e = e0 + t + k * 256;
        if (e - e0 < cnt) {
            const int d = ei[e];
            const int s = ei[E + e];
            const float w = ew[e];
            const int b = d >> 7;
            const int dl = d & 127;
            const int p = atomicAdd(&cur[b], 1);
            stage[p] = make_int2((dl << 17) | s, __float_as_int(w));
        }
    }
    __syncthreads();

    for (int i = t; i < cnt; i += 256) {
        int lo = 0, hi = NBK - 1;
#pragma unroll
        for (int it = 0; it < 10; ++it) {
            const int mid = (lo + hi + 1) >> 1;
            if (ls[mid] <= i) lo = mid; else hi = mid - 1;
        }
        sorted[gb[lo] + (i - ls[lo])] = stage[i];
    }
}

// --------------------------------------------------------------------------
// agg v5: one block (512 thr, 8 waves) per bucket. Per chunk (<=CAP edges):
//   pass1: LDS hist of local dst (int atomics), 128-entry block scan,
//   pass2: LDS scatter -> meta2[] fine-sorted by local dst.
// Then each wave owns rows wv, wv+8, ...: contiguous segment in meta2, edges
// processed 2 at a time (half-wave each, 32 lanes x bf16x2 = one 128B line),
// REGISTER fp32 accumulation, shfl_xor combine, direct coalesced row write.
// No fp32 atomics. Covers all rows (zeros for empty) -> no agg memset.
// --------------------------------------------------------------------------
__global__ __launch_bounds__(512) void agg_kernel(
        const unsigned int* __restrict__ xb2,   // bf16x2 per uint, row stride 32
        const int2* __restrict__ sorted,
        const int* __restrict__ boffs,
        float* __restrict__ agg, int N) {
    __shared__ int2 meta2[CAP];             // 20 KB
    __shared__ int lcnt[BKT];
    __shared__ int lincl[BKT];
    __shared__ int lcur[BKT];

    const int t = threadIdx.x;
    const int b = blockIdx.x;
    const int node0 = b << 7;
    const int lane = t & 63;
    const int wv = t >> 6;                  // 0..7
    const int half = lane >> 5;
    const int cl = lane & 31;               // uint index within row (2 channels)

    const int beg = boffs[b];
    const int end = boffs[b + 1];

    int chunk = beg;
    do {
        const int cc = (end - chunk < CAP) ? (end - chunk) : CAP;  // may be 0

        for (int i = t; i < BKT; i += 512) lcnt[i] = 0;
        __syncthreads();

        // pass 1: histogram of local dst (coalesced global reads)
        for (int i = t; i < cc; i += 512)
            atomicAdd(&lcnt[sorted[chunk + i].x >> 17], 1);
        __syncthreads();

        // 128-entry inclusive scan (Hillis-Steele, threads 0..127)
        if (t < BKT) lincl[t] = lcnt[t];
        __syncthreads();
        for (int off = 1; off < BKT; off <<= 1) {
            int v = 0;
            if (t < BKT && t >= off) v = lincl[t - off];
            __syncthreads();
            if (t < BKT && t >= off) lincl[t] += v;
            __syncthreads();
        }
        if (t < BKT) lcur[t] = lincl[t] - lcnt[t];   // exclusive start
        __syncthreads();

        // pass 2: LDS scatter into fine-sorted order
        for (int i = t; i < cc; i += 512) {
            const int2 m = sorted[chunk + i];
            const int dl = m.x >> 17;
            const int p = atomicAdd(&lcur[dl], 1);
            meta2[p] = make_int2(m.x & 0x1FFFF, m.y);
        }
        __syncthreads();

        // aggregate: wave wv handles rows wv, wv+8, ... (16 rows)
        const bool first = (chunk == beg);
        for (int r = wv; r < BKT; r += 8) {
            const int s1 = lincl[r];
            const int s0 = s1 - lcnt[r];
            float ax = 0.f, ay = 0.f;
            for (int j = s0 + half; j < s1; j += 2) {
                const int2 m = meta2[j];            // same addr in half-wave: broadcast
                const float w = __int_as_float(m.y);
                const unsigned u = xb2[(unsigned)m.x * 32u + cl];   // 128B line
                ax += w * __int_as_float((int)(u << 16));
                ay += w * __int_as_float((int)(u & 0xffff0000u));
            }
            ax += __shfl_xor(ax, 32);
            ay += __shfl_xor(ay, 32);
            const int node = node0 + r;
            if (half == 0 && node < N) {
                float2* dst = (float2*)(agg + (size_t)node * C + 2 * cl);
                if (first) {
                    *dst = make_float2(ax, ay);
                } else {
                    float2 o = *dst;
                    o.x += ax; o.y += ay;
                    *dst = o;
                }
            }
        }
        chunk += CAP;
        __syncthreads();            // protect lcnt reuse next chunk
    } while (chunk < end);
}

// --------------------------------------------------------------------------
// fallback (ws too small / N too big): R2 atomic scatter.
// --------------------------------------------------------------------------
__global__ __launch_bounds__(256) void scatter_kernel(
        const float* __restrict__ x, const int* __restrict__ ei,
        const float* __restrict__ ew, float* __restrict__ agg, int E) {
    const int lane = threadIdx.x & 63;
    const int wid = (blockIdx.x * blockDim.x + threadIdx.x) >> 6;
    const int nw = (gridDim.x * blockDim.x) >> 6;
    for (int base = wid * 64; base < E; base += nw * 64) {
        const int e = base + lane;
        int dst = 0, src = 0; float w = 0.f;
        if (e < E) { dst = ei[e]; src = ei[E + e]; w = ew[e]; }
        const int cnt = min(64, E - base);
        for (int j = 0; j < cnt; ++j) {
            const int d = __shfl(dst, j);
            const int s = __shfl(src, j);
            const float wj = __shfl(w, j);
            atomicAdd(&agg[d * C + lane], x[s * C + lane] * wj);
        }
    }
}

// --------------------------------------------------------------------------
// proj: out = [x | agg] @ [Ws | Wn]^T + bias as K=128 bf16 MFMA GEMM.
// --------------------------------------------------------------------------
__device__ inline bf16x8 cvt8(const float* __restrict__ p) {
    f32x4 lo = *(const f32x4*)p;
    f32x4 hi = *(const f32x4*)(p + 4);
    union { bf16x8 v; __hip_bfloat16 e[8]; } u;
#pragma unroll
    for (int j = 0; j < 4; ++j) u.e[j] = __float2bfloat16(lo[j]);
#pragma unroll
    for (int j = 0; j < 4; ++j) u.e[4 + j] = __float2bfloat16(hi[j]);
    return u.v;
}

__global__ __launch_bounds__(256) void proj_kernel(
        const float* __restrict__ x, const float* __restrict__ agg,
        const float* __restrict__ Ws, const float* __restrict__ bs,
        const float* __restrict__ Wn, const float* __restrict__ bn,
        float* __restrict__ out, int N) {
    const int lane = threadIdx.x & 63;
    const int wid = (blockIdx.x * blockDim.x + threadIdx.x) >> 6;
    const int l15 = lane & 15;
    const int quad = lane >> 4;
    const int nTiles = N >> 4;
    if (wid >= nTiles) return;
    const int m0 = wid << 4;

    bf16x8 bsf[4][2], bnf[4][2];
#pragma unroll
    for (int tt = 0; tt < 4; ++tt) {
        const int o = tt * 16 + l15;
#pragma unroll
        for (int h = 0; h < 2; ++h) {
            bsf[tt][h] = cvt8(Ws + o * C + h * 32 + quad * 8);
            bnf[tt][h] = cvt8(Wn + o * C + h * 32 + quad * 8);
        }
    }

    const int m = m0 + l15;
    bf16x8 ax[2], ag[2];
#pragma unroll
    for (int h = 0; h < 2; ++h) {
        ax[h] = cvt8(x + m * C + h * 32 + quad * 8);
        ag[h] = cvt8(agg + m * C + h * 32 + quad * 8);
    }

#pragma unroll
    for (int tt = 0; tt < 4; ++tt) {
        f32x4 acc = {0.f, 0.f, 0.f, 0.f};
        acc = __builtin_amdgcn_mfma_f32_16x16x32_bf16(ax[0], bsf[tt][0], acc, 0, 0, 0);
        acc = __builtin_amdgcn_mfma_f32_16x16x32_bf16(ax[1], bsf[tt][1], acc, 0, 0, 0);
        acc = __builtin_amdgcn_mfma_f32_16x16x32_bf16(ag[0], bnf[tt][0], acc, 0, 0, 0);
        acc = __builtin_amdgcn_mfma_f32_16x16x32_bf16(ag[1], bnf[tt][1], acc, 0, 0, 0);
        const int o = tt * 16 + l15;
        const float bias = bs[o] + bn[o];
#pragma unroll
        for (int r = 0; r < 4; ++r)
            out[(m0 + quad * 4 + r) * C + o] = acc[r] + bias;
    }
}

extern "C" void kernel_launch(void* const* d_in, const int* in_sizes, int n_in,
                              void* d_out, int out_size, void* d_ws, size_t ws_size,
                              hipStream_t stream) {
    const float* x  = (const float*)d_in[0];
    const int*   ei = (const int*)d_in[1];
    const float* ew = (const float*)d_in[2];
    const float* Ws = (const float*)d_in[3];
    const float* bs = (const float*)d_in[4];
    const float* Wn = (const float*)d_in[5];
    const float* bn = (const float*)d_in[6];

    const int N = in_sizes[0] / C;   // 100000
    const int E = in_sizes[2];       // 1600000
    const int NBK = (N + BKT - 1) / BKT;   // 782

    char* p = (char*)d_ws;
    float* agg = (float*)p;                 p += (size_t)N * C * sizeof(float);   // 25.6MB
    unsigned short* xb = (unsigned short*)p; p += (size_t)N * C * sizeof(short);  // 12.8MB
    int2* sorted = (int2*)p;                p += (size_t)E * sizeof(int2);        // 12.8MB
    int* bhist = (int*)p;                   p += (size_t)MAXB * sizeof(int);
    int* boffs = (int*)p;                   p += (size_t)(MAXB + 1) * sizeof(int);
    int* bcur = (int*)p;                    p += (size_t)MAXB * sizeof(int);
    const size_t needed = (size_t)(p - (char*)d_ws);

    const int nTiles = N / 16;
    const int projBlocks = (nTiles + 3) / 4;

    if (needed <= ws_size && N <= (1 << 17) && NBK <= MAXB) {
        const int n4 = N * C / 4;
        hipMemsetAsync(bhist, 0, (size_t)NBK * sizeof(int), stream);
        prep_kernel<<<1024, 256, 0, stream>>>(ei, bhist, E, NBK, x, xb, n4);
        scan_kernel<<<1, 1024, 0, stream>>>(bhist, boffs, bcur, NBK);
        bin_kernel<<<(E + BINT - 1) / BINT, 256, 0, stream>>>(ei, ew, bcur, bhist,
                                                              sorted, E, NBK);
        agg_kernel<<<NBK, 512, 0, stream>>>((const unsigned int*)xb, sorted,
                                            boffs, agg, N);
    } else {
        hipMemsetAsync(agg, 0, (size_t)N * C * sizeof(float), stream);
        scatter_kernel<<<2048, 256, 0, stream>>>(x, ei, ew, agg, E);
    }

    proj_kernel<<<projBlocks, 256, 0, stream>>>(x, agg, Ws, bs, Wn, bn,
                                                (float*)d_out, N);
}

// Round 10
// 230.855 us; speedup vs baseline: 3.8431x; 1.1106x over previous
//
#include <hip/hip_runtime.h>
#include <hip/hip_bf16.h>

// SAGEConv: out = x @ W_self^T + b_self + segsum(x[col]*w, row) @ W_neigh^T + b_neigh
// N=100000, E=1600000, C=64. fp32 tensors; edge_index int32 [2*E] (dst|src); out fp32.
//
// R10: R9 (fine LDS sort + register accumulation, zero fp32 atomics) cut agg
// 696->64us. agg now gather-latency-bound (VALU 21%, HBM 21%, MLP~1).
// v6: quarter-wave per edge (16 lanes x ushort4 = 128B row) -> 1 load instr
// per 4 edges, manual unroll-2 -> 2 loads in flight. shfl_xor(16|32) reduce.

#define C 64
#define BKT 128                 // nodes per bucket
#define MAXB 800                // max bucket count supported by static LDS
#define BINT 6144               // edges per bin block (24 per thread)
#define CAP 2560                // agg: edges sorted per chunk (bucket avg 2046)

typedef __attribute__((ext_vector_type(8))) short bf16x8;
typedef __attribute__((ext_vector_type(4))) float f32x4;

__device__ inline unsigned short f2bf(float f) {
    union { __hip_bfloat16 h; unsigned short u; } c;
    c.h = __float2bfloat16(f);
    return c.u;
}

__device__ inline float bfhi(unsigned short u) {
    return __int_as_float(((int)u) << 16);
}

// --------------------------------------------------------------------------
// prep: bucket histogram (LDS pre-agg) + x -> bf16 conversion.
// --------------------------------------------------------------------------
__global__ __launch_bounds__(256) void prep_kernel(
        const int* __restrict__ ei, int* __restrict__ bhist, int E, int NBK,
        const float* __restrict__ x, unsigned short* __restrict__ xb, int n4) {
    __shared__ int lh[MAXB];
    const int t = threadIdx.x;
    for (int i = t; i < NBK; i += 256) lh[i] = 0;
    __syncthreads();
    const int gtid = blockIdx.x * 256 + t;
    const int gs = gridDim.x * 256;
    for (int e = gtid; e < E; e += gs)
        atomicAdd(&lh[ei[e] >> 7], 1);
    __syncthreads();
    for (int i = t; i < NBK; i += 256)
        if (lh[i]) atomicAdd(&bhist[i], lh[i]);
    const float4* x4 = (const float4*)x;
    ushort4* xb4 = (ushort4*)xb;
    for (int i = gtid; i < n4; i += gs) {
        float4 v = x4[i];
        ushort4 o;
        o.x = f2bf(v.x); o.y = f2bf(v.y); o.z = f2bf(v.z); o.w = f2bf(v.w);
        xb4[i] = o;
    }
}

// --------------------------------------------------------------------------
// scan: exclusive scan of bhist[NBK] -> boffs[NBK+1], copy to bcur. 1 block.
// --------------------------------------------------------------------------
__global__ __launch_bounds__(1024) void scan_kernel(
        const int* __restrict__ bhist, int* __restrict__ boffs,
        int* __restrict__ bcur, int NBK) {
    __shared__ int s[1024];
    const int t = threadIdx.x;
    s[t] = (t < NBK) ? bhist[t] : 0;
    __syncthreads();
    for (int off = 1; off < 1024; off <<= 1) {
        int v = 0;
        if (t >= off) v = s[t - off];
        __syncthreads();
        if (t >= off) s[t] += v;
        __syncthreads();
    }
    if (t < NBK) {
        int e = (t > 0) ? s[t - 1] : 0;
        boffs[t] = e;
        bcur[t] = e;
        if (t == NBK - 1) boffs[NBK] = s[t];
    }
}

// --------------------------------------------------------------------------
// bin: coarse counting sort by 128-node bucket, LDS-staged coalesced writes.
// --------------------------------------------------------------------------
__global__ __launch_bounds__(256) void bin_kernel(
        const int* __restrict__ ei, const float* __restrict__ ew,
        int* __restrict__ bcur, const int* __restrict__ unused,
        int2* __restrict__ sorted, int E, int NBK) {
    __shared__ int2 stage[BINT];            // 48 KB
    __shared__ int h[MAXB];
    __shared__ int ls[MAXB + 1];
    __shared__ int gb[MAXB];
    __shared__ int cur[MAXB];
    __shared__ int part[256];

    const int t = threadIdx.x;
    const int e0 = blockIdx.x * BINT;
    const int cnt = min(BINT, E - e0);

    for (int i = t; i < NBK; i += 256) h[i] = 0;
    __syncthreads();

#pragma unroll
    for (int k = 0; k < BINT / 256; ++k) {
        const int e = e0 + t + k * 256;
        if (e - e0 < cnt) atomicAdd(&h[ei[e] >> 7], 1);
    }
    __syncthreads();

    int vloc[4]; int s0 = 0;
#pragma unroll
    for (int k = 0; k < 4; ++k) {
        const int idx = t * 4 + k;
        vloc[k] = (idx < NBK) ? h[idx] : 0;
        s0 += vloc[k];
    }
    part[t] = s0;
    __syncthreads();
    for (int off = 1; off < 256; off <<= 1) {
        int v = 0;
        if (t >= off) v = part[t - off];
        __syncthreads();
        if (t >= off) part[t] += v;
        __syncthreads();
    }
    int run = (t > 0) ? part[t - 1] : 0;
#pragma unroll
    for (int k = 0; k < 4; ++k) {
        const int idx = t * 4 + k;
        if (idx < NBK) ls[idx] = run;
        run += vloc[k];
    }
    if (t == 255) ls[NBK] = part[255];
    __syncthreads();

    for (int i = t; i < NBK; i += 256) {
        const int hh = ls[i + 1] - ls[i];
        gb[i] = hh ? atomicAdd(&bcur[i], hh) : 0;
        cur[i] = ls[i];
    }
    __syncthreads();

#pragma unroll
    for (int k = 0; k < BINT / 256; ++k) {
        const int e = e0 + t + k * 256;
        if (e - e0 < cnt) {
            const int d = ei[e];
            const int s = ei[E + e];
            const float w = ew[e];
            const int b = d >> 7;
            const int dl = d & 127;
            const int p = atomicAdd(&cur[b], 1);
            stage[p] = make_int2((dl << 17) | s, __float_as_int(w));
        }
    }
    __syncthreads();

    for (int i = t; i < cnt; i += 256) {
        int lo = 0, hi = NBK - 1;
#pragma unroll
        for (int it = 0; it < 10; ++it) {
            const int mid = (lo + hi + 1) >> 1;
            if (ls[mid] <= i) lo = mid; else hi = mid - 1;
        }
        sorted[gb[lo] + (i - ls[lo])] = stage[i];
    }
}

// --------------------------------------------------------------------------
// agg v6: one block (512 thr, 8 waves) per bucket. Fine counting sort in LDS
// (int atomics only), then wave wv owns rows wv, wv+8, ...: QUARTER-wave per
// edge (16 lanes x ushort4 = 128B row), manual unroll-2 (2 gathers in
// flight), register fp32 accumulation, shfl_xor(16|32) reduce, float4 row
// write by lanes 0-15. Zero fp32 atomics; covers all rows -> no agg memset.
// --------------------------------------------------------------------------
__global__ __launch_bounds__(512) void agg_kernel(
        const ushort4* __restrict__ xb4,    // row stride 16 ushort4
        const int2* __restrict__ sorted,
        const int* __restrict__ boffs,
        float* __restrict__ agg, int N) {
    __shared__ int2 meta2[CAP];             // 20 KB
    __shared__ int lcnt[BKT];
    __shared__ int lincl[BKT];
    __shared__ int lcur[BKT];

    const int t = threadIdx.x;
    const int b = blockIdx.x;
    const int node0 = b << 7;
    const int lane = t & 63;
    const int wv = t >> 6;                  // 0..7
    const int q = lane >> 4;                // quarter id 0..3
    const int cq = lane & 15;               // ushort4 index within row

    const int beg = boffs[b];
    const int end = boffs[b + 1];

    int chunk = beg;
    do {
        const int cc = (end - chunk < CAP) ? (end - chunk) : CAP;  // may be 0

        for (int i = t; i < BKT; i += 512) lcnt[i] = 0;
        __syncthreads();

        // pass 1: histogram of local dst (coalesced global reads)
        for (int i = t; i < cc; i += 512)
            atomicAdd(&lcnt[sorted[chunk + i].x >> 17], 1);
        __syncthreads();

        // 128-entry inclusive scan (Hillis-Steele, threads 0..127)
        if (t < BKT) lincl[t] = lcnt[t];
        __syncthreads();
        for (int off = 1; off < BKT; off <<= 1) {
            int v = 0;
            if (t < BKT && t >= off) v = lincl[t - off];
            __syncthreads();
            if (t < BKT && t >= off) lincl[t] += v;
            __syncthreads();
        }
        if (t < BKT) lcur[t] = lincl[t] - lcnt[t];   // exclusive start
        __syncthreads();

        // pass 2: LDS scatter into fine-sorted order (src, w)
        for (int i = t; i < cc; i += 512) {
            const int2 m = sorted[chunk + i];
            const int dl = m.x >> 17;
            const int p = atomicAdd(&lcur[dl], 1);
            meta2[p] = make_int2(m.x & 0x1FFFF, m.y);
        }
        __syncthreads();

        // aggregate: wave wv handles rows wv, wv+8, ... (16 rows)
        const bool first = (chunk == beg);
        for (int r = wv; r < BKT; r += 8) {
            const int s1 = lincl[r];
            const int s0 = s1 - lcnt[r];
            float a0 = 0.f, a1 = 0.f, a2 = 0.f, a3 = 0.f;
            int j = s0 + q;
            // unroll-2: both gathers issued before either's FMAs
            for (; j + 4 < s1; j += 8) {
                const int2 m0 = meta2[j];
                const int2 m1 = meta2[j + 4];
                const ushort4 u0 = xb4[(unsigned)m0.x * 16u + cq];
                const ushort4 u1 = xb4[(unsigned)m1.x * 16u + cq];
                const float w0 = __int_as_float(m0.y);
                const float w1 = __int_as_float(m1.y);
                a0 += w0 * bfhi(u0.x); a1 += w0 * bfhi(u0.y);
                a2 += w0 * bfhi(u0.z); a3 += w0 * bfhi(u0.w);
                a0 += w1 * bfhi(u1.x); a1 += w1 * bfhi(u1.y);
                a2 += w1 * bfhi(u1.z); a3 += w1 * bfhi(u1.w);
            }
            if (j < s1) {
                const int2 m0 = meta2[j];
                const ushort4 u0 = xb4[(unsigned)m0.x * 16u + cq];
                const float w0 = __int_as_float(m0.y);
                a0 += w0 * bfhi(u0.x); a1 += w0 * bfhi(u0.y);
                a2 += w0 * bfhi(u0.z); a3 += w0 * bfhi(u0.w);
            }
            // reduce across the 4 quarters
            a0 += __shfl_xor(a0, 16); a0 += __shfl_xor(a0, 32);
            a1 += __shfl_xor(a1, 16); a1 += __shfl_xor(a1, 32);
            a2 += __shfl_xor(a2, 16); a2 += __shfl_xor(a2, 32);
            a3 += __shfl_xor(a3, 16); a3 += __shfl_xor(a3, 32);
            const int node = node0 + r;
            if (q == 0 && node < N) {
                float4* dst = (float4*)(agg + (size_t)node * C + 4 * cq);
                if (first) {
                    *dst = make_float4(a0, a1, a2, a3);
                } else {
                    float4 o = *dst;
                    o.x += a0; o.y += a1; o.z += a2; o.w += a3;
                    *dst = o;
                }
            }
        }
        chunk += CAP;
        __syncthreads();            // protect lcnt reuse next chunk
    } while (chunk < end);
}

// --------------------------------------------------------------------------
// fallback (ws too small / N too big): R2 atomic scatter.
// --------------------------------------------------------------------------
__global__ __launch_bounds__(256) void scatter_kernel(
        const float* __restrict__ x, const int* __restrict__ ei,
        const float* __restrict__ ew, float* __restrict__ agg, int E) {
    const int lane = threadIdx.x & 63;
    const int wid = (blockIdx.x * blockDim.x + threadIdx.x) >> 6;
    const int nw = (gridDim.x * blockDim.x) >> 6;
    for (int base = wid * 64; base < E; base += nw * 64) {
        const int e = base + lane;
        int dst = 0, src = 0; float w = 0.f;
        if (e < E) { dst = ei[e]; src = ei[E + e]; w = ew[e]; }
        const int cnt = min(64, E - base);
        for (int j = 0; j < cnt; ++j) {
            const int d = __shfl(dst, j);
            const int s = __shfl(src, j);
            const float wj = __shfl(w, j);
            atomicAdd(&agg[d * C + lane], x[s * C + lane] * wj);
        }
    }
}

// --------------------------------------------------------------------------
// proj: out = [x | agg] @ [Ws | Wn]^T + bias as K=128 bf16 MFMA GEMM.
// --------------------------------------------------------------------------
__device__ inline bf16x8 cvt8(const float* __restrict__ p) {
    f32x4 lo = *(const f32x4*)p;
    f32x4 hi = *(const f32x4*)(p + 4);
    union { bf16x8 v; __hip_bfloat16 e[8]; } u;
#pragma unroll
    for (int j = 0; j < 4; ++j) u.e[j] = __float2bfloat16(lo[j]);
#pragma unroll
    for (int j = 0; j < 4; ++j) u.e[4 + j] = __float2bfloat16(hi[j]);
    return u.v;
}

__global__ __launch_bounds__(256) void proj_kernel(
        const float* __restrict__ x, const float* __restrict__ agg,
        const float* __restrict__ Ws, const float* __restrict__ bs,
        const float* __restrict__ Wn, const float* __restrict__ bn,
        float* __restrict__ out, int N) {
    const int lane = threadIdx.x & 63;
    const int wid = (blockIdx.x * blockDim.x + threadIdx.x) >> 6;
    const int l15 = lane & 15;
    const int quad = lane >> 4;
    const int nTiles = N >> 4;
    if (wid >= nTiles) return;
    const int m0 = wid << 4;

    bf16x8 bsf[4][2], bnf[4][2];
#pragma unroll
    for (int tt = 0; tt < 4; ++tt) {
        const int o = tt * 16 + l15;
#pragma unroll
        for (int h = 0; h < 2; ++h) {
            bsf[tt][h] = cvt8(Ws + o * C + h * 32 + quad * 8);
            bnf[tt][h] = cvt8(Wn + o * C + h * 32 + quad * 8);
        }
    }

    const int m = m0 + l15;
    bf16x8 ax[2], ag[2];
#pragma unroll
    for (int h = 0; h < 2; ++h) {
        ax[h] = cvt8(x + m * C + h * 32 + quad * 8);
        ag[h] = cvt8(agg + m * C + h * 32 + quad * 8);
    }

#pragma unroll
    for (int tt = 0; tt < 4; ++tt) {
        f32x4 acc = {0.f, 0.f, 0.f, 0.f};
        acc = __builtin_amdgcn_mfma_f32_16x16x32_bf16(ax[0], bsf[tt][0], acc, 0, 0, 0);
        acc = __builtin_amdgcn_mfma_f32_16x16x32_bf16(ax[1], bsf[tt][1], acc, 0, 0, 0);
        acc = __builtin_amdgcn_mfma_f32_16x16x32_bf16(ag[0], bnf[tt][0], acc, 0, 0, 0);
        acc = __builtin_amdgcn_mfma_f32_16x16x32_bf16(ag[1], bnf[tt][1], acc, 0, 0, 0);
        const int o = tt * 16 + l15;
        const float bias = bs[o] + bn[o];
#pragma unroll
        for (int r = 0; r < 4; ++r)
            out[(m0 + quad * 4 + r) * C + o] = acc[r] + bias;
    }
}

extern "C" void kernel_launch(void* const* d_in, const int* in_sizes, int n_in,
                              void* d_out, int out_size, void* d_ws, size_t ws_size,
                              hipStream_t stream) {
    const float* x  = (const float*)d_in[0];
    const int*   ei = (const int*)d_in[1];
    const float* ew = (const float*)d_in[2];
    const float* Ws = (const float*)d_in[3];
    const float* bs = (const float*)d_in[4];
    const float* Wn = (const float*)d_in[5];
    const float* bn = (const float*)d_in[6];

    const int N = in_sizes[0] / C;   // 100000
    const int E = in_sizes[2];       // 1600000
    const int NBK = (N + BKT - 1) / BKT;   // 782

    char* p = (char*)d_ws;
    float* agg = (float*)p;                 p += (size_t)N * C * sizeof(float);   // 25.6MB
    unsigned short* xb = (unsigned short*)p; p += (size_t)N * C * sizeof(short);  // 12.8MB
    int2* sorted = (int2*)p;                p += (size_t)E * sizeof(int2);        // 12.8MB
    int* bhist = (int*)p;                   p += (size_t)MAXB * sizeof(int);
    int* boffs = (int*)p;                   p += (size_t)(MAXB + 1) * sizeof(int);
    int* bcur = (int*)p;                    p += (size_t)MAXB * sizeof(int);
    const size_t needed = (size_t)(p - (char*)d_ws);

    const int nTiles = N / 16;
    const int projBlocks = (nTiles + 3) / 4;

    if (needed <= ws_size && N <= (1 << 17) && NBK <= MAXB) {
        const int n4 = N * C / 4;
        hipMemsetAsync(bhist, 0, (size_t)NBK * sizeof(int), stream);
        prep_kernel<<<1024, 256, 0, stream>>>(ei, bhist, E, NBK, x, xb, n4);
        scan_kernel<<<1, 1024, 0, stream>>>(bhist, boffs, bcur, NBK);
        bin_kernel<<<(E + BINT - 1) / BINT, 256, 0, stream>>>(ei, ew, bcur, bhist,
                                                              sorted, E, NBK);
        agg_kernel<<<NBK, 512, 0, stream>>>((const ushort4*)xb, sorted,
                                            boffs, agg, N);
    } else {
        hipMemsetAsync(agg, 0, (size_t)N * C * sizeof(float), stream);
        scatter_kernel<<<2048, 256, 0, stream>>>(x, ei, ew, agg, E);
    }

    proj_kernel<<<projBlocks, 256, 0, stream>>>(x, agg, Ws, bs, Wn, bn,
                                                (float*)d_out, N);
}